// Round 18
// baseline (249.198 us; speedup 1.0000x reference)
//
#include <hip/hip_runtime.h>
#include <hip/hip_bf16.h>
#include <cmath>

// ---------------- types / helpers ----------------
typedef __bf16 bf16x8 __attribute__((ext_vector_type(8)));
typedef float  f32x4  __attribute__((ext_vector_type(4)));

#define LDS_AS __attribute__((address_space(3)))
#define GLB_AS __attribute__((address_space(1)))

__device__ __forceinline__ void gll16(const void* g, void* l) {
    __builtin_amdgcn_global_load_lds((const GLB_AS unsigned int*)g,
                                     (LDS_AS unsigned int*)l, 16, 0, 0);
}

__device__ __forceinline__ f32x4 mfma16(bf16x8 a, bf16x8 b, f32x4 c) {
    return __builtin_amdgcn_mfma_f32_16x16x32_bf16(a, b, c, 0, 0, 0);
}

__device__ __forceinline__ unsigned short f2bf(float f) {
    __hip_bfloat16 b = __float2bfloat16(f);
    return *reinterpret_cast<unsigned short*>(&b);
}

// ---- 128-B-row swizzle (proven 0-conflict; used by gemm_sk and flash) ----
__device__ __forceinline__ bf16x8 swzfrag(const __hip_bfloat16* __restrict__ lds,
                                          int row, int cb)
{
    const int addr = row * 128 + (cb ^ ((row & 7) << 4));
    return *(const bf16x8*)((const char*)lds + addr);
}

// Stage a 128-row x 64-byte (8 KB) BK=32 tile, LINEAR source and LINEAR LDS
// (m97/r1-exact addressing: lane-contiguous global reads — r18 tests the
// hypothesis that the XOR pre-swizzled source halves gll16 gather throughput).
__device__ __forceinline__ void stage128x64B_lin(const char* __restrict__ base, int pitch,
                                                 char* __restrict__ lds, int t)
{
#pragma unroll
    for (int i = 0; i < 2; ++i) {
        const int d   = i * 4096 + t * 16;
        const int row = d >> 6;       // 64-B rows; 4 lanes cover one row contiguously
        const int x   = d & 63;
        gll16(base + (size_t)row * pitch + x, lds + d);
    }
}

// Stage a 64-row x 128-byte tile into LDS, XOR-swizzled (flash). 256 threads.
__device__ __forceinline__ void stage64x128B(const char* __restrict__ base, int pitch,
                                             char* __restrict__ lds, int t)
{
#pragma unroll
    for (int i = 0; i < 2; ++i) {
        const int d   = i * 4096 + t * 16;
        const int row = d >> 7;
        const int x   = d & 127;
        const int gx  = x ^ ((row & 7) << 4);
        gll16(base + (size_t)row * pitch + gx, lds + d);
    }
}

// 128 rows x 128 bytes (16 KB), 256 threads x 4 x 16B. (gemm_sk)
__device__ __forceinline__ void stage128x128B(const char* __restrict__ base, int pitch,
                                              char* __restrict__ lds, int t)
{
#pragma unroll
    for (int i = 0; i < 4; ++i) {
        const int d   = i * 4096 + t * 16;
        const int row = d >> 7;
        const int x   = d & 127;
        const int gx  = x ^ ((row & 7) << 4);
        gll16(base + (size_t)row * pitch + gx, lds + d);
    }
}

// dims
#define TB   2
#define TT   2048
#define TD   1024
#define TH   16
#define TDH  64
#define TDFF 4096
#define TM   4096   // B*T

// ---------------- fused fp32 -> bf16 conversion for ALL 4 weight tensors ---------
__global__ __launch_bounds__(256)
void cvt4_kernel(const float* __restrict__ s0, const float* __restrict__ s1,
                 const float* __restrict__ s2, const float* __restrict__ s3,
                 __hip_bfloat16* __restrict__ d0, __hip_bfloat16* __restrict__ d1,
                 __hip_bfloat16* __restrict__ d2, __hip_bfloat16* __restrict__ d3)
{
    const int i = blockIdx.x * 256 + threadIdx.x;
    const float* src; __hip_bfloat16* dst; int off;
    if (i < 786432)       { src = s0; dst = d0; off = 0; }        // w_qkv  3M f4
    else if (i < 1048576) { src = s1; dst = d1; off = 786432; }   // w_out
    else if (i < 2097152) { src = s2; dst = d2; off = 1048576; }  // w1
    else                  { src = s3; dst = d3; off = 2097152; }  // w2
    const int j = i - off;
    float4 v = ((const float4*)src)[j];
    ushort4 o;
    o.x = f2bf(v.x); o.y = f2bf(v.y); o.z = f2bf(v.z); o.w = f2bf(v.w);
    ((ushort4*)dst)[j] = o;
}

// ---------------- LayerNorm (D=1024), out bf16 ----------------
__global__ __launch_bounds__(256)
void ln_kernel(const float* __restrict__ x, const float* __restrict__ g,
               const float* __restrict__ b, __hip_bfloat16* __restrict__ out)
{
    const int row = blockIdx.x;
    const int t = threadIdx.x;
    const float4 v = *(const float4*)(x + (size_t)row * TD + t * 4);
    float s  = v.x + v.y + v.z + v.w;
    float ss = v.x*v.x + v.y*v.y + v.z*v.z + v.w*v.w;
#pragma unroll
    for (int d = 1; d < 64; d <<= 1) { s += __shfl_xor(s, d); ss += __shfl_xor(ss, d); }
    __shared__ float red[8];
    const int wv = t >> 6, lane = t & 63;
    if (lane == 0) { red[wv] = s; red[4 + wv] = ss; }
    __syncthreads();
    s  = red[0] + red[1] + red[2] + red[3];
    ss = red[4] + red[5] + red[6] + red[7];
    const float mean = s * (1.0f / TD);
    const float var  = ss * (1.0f / TD) - mean * mean;
    const float rstd = rsqrtf(var + 1e-5f);
    const float4 gv = *(const float4*)(g + t * 4);
    const float4 bv = *(const float4*)(b + t * 4);
    ushort4 o;
    o.x = f2bf((v.x - mean) * rstd * gv.x + bv.x);
    o.y = f2bf((v.y - mean) * rstd * gv.y + bv.y);
    o.z = f2bf((v.z - mean) * rstd * gv.z + bv.z);
    o.w = f2bf((v.w - mean) * rstd * gv.w + bv.w);
    *(ushort4*)(out + (size_t)row * TD + t * 4) = o;
}

// ---------------- GEMM BK=32 high-occupancy (QKV, FFN1), LINEAR staging -------
// r18: A/B-test vs r17 isolating the SOURCE-ADDRESS variable. m97 (identical
// structure, linear source, linear LDS, 1.7e7 read conflicts) stages at ~21
// B/cyc/CU; our swizzled-source variant at ~10-12. This kernel: linear
// lane-contiguous gll16 into linear [128][32] LDS; fragment reads direct
// (8-way bank conflict expected, ~+200 cyc/iter, cheap vs a 2x staging gain).
// Everything else r17-exact: dbuf 32 KB -> 4-5 blocks/CU, counted vmcnt(4),
// setprio, 2D XCD-chunked bijective remap. Accumulation order identical ->
// bit-identical output.
template<int EPI>   // 0 = QKV scatter, 2 = GELU -> bf16
__global__ __launch_bounds__(256)
void gemm_bt32(const __hip_bfloat16* __restrict__ A, const __hip_bfloat16* __restrict__ Bw,
               const float* __restrict__ bias,
               __hip_bfloat16* __restrict__ outb,
               __hip_bfloat16* __restrict__ qb, __hip_bfloat16* __restrict__ kb,
               __hip_bfloat16* __restrict__ vtb,
               int M, int N, int K)
{
    __shared__ __hip_bfloat16 ldsA[2][128 * 32];   // 2 x 8 KB
    __shared__ __hip_bfloat16 ldsB[2][128 * 32];   // 2 x 8 KB  (total 32 KB)
    const int t = threadIdx.x;
    const int lane = t & 63, wv = t >> 6;
    const int wr = wv >> 1, wc = wv & 1;
    const int l15 = lane & 15, lg = lane >> 4;

    // 2D XCD-chunked remap (bijective for gridDim.y==32, gridDim.x multiple of 8)
    const int L   = blockIdx.y * gridDim.x + blockIdx.x;
    const int xcd = L & 7;
    const int sl  = (L >> 3) & 31;
    const int gen = L >> 8;
    const int bm  = xcd * 4 + (sl & 3);
    const int bn  = gen * 8 + (sl >> 2);

    f32x4 acc[4][4] = {};

    const char* Ab = (const char*)(A  + (size_t)bm * 128 * K);
    const char* Bb = (const char*)(Bw + (size_t)bn * 128 * K);
    const int pitch = K * 2;

    const int nt = K >> 5;
    stage128x64B_lin(Ab, pitch, (char*)ldsA[0], t);
    stage128x64B_lin(Bb, pitch, (char*)ldsB[0], t);

    for (int it = 0; it < nt; ++it) {
        if (it + 1 < nt) {
            const size_t koff = (size_t)(it + 1) * 64;   // 32 elems = 64 B per row
            stage128x64B_lin(Ab + koff, pitch, (char*)ldsA[(it + 1) & 1], t);
            stage128x64B_lin(Bb + koff, pitch, (char*)ldsB[(it + 1) & 1], t);
            asm volatile("s_waitcnt vmcnt(4)" ::: "memory");   // tile(it) landed
        } else {
            asm volatile("s_waitcnt vmcnt(0)" ::: "memory");
        }
        __builtin_amdgcn_s_barrier();
        __builtin_amdgcn_sched_barrier(0);
        const __hip_bfloat16* bufA = ldsA[it & 1];
        const __hip_bfloat16* bufB = ldsB[it & 1];
        bf16x8 af[4], bfr[4];
#pragma unroll
        for (int mf = 0; mf < 4; ++mf)
            af[mf] = *(const bf16x8*)(bufA + (wr * 64 + mf * 16 + l15) * 32 + lg * 8);
#pragma unroll
        for (int nf = 0; nf < 4; ++nf)
            bfr[nf] = *(const bf16x8*)(bufB + (wc * 64 + nf * 16 + l15) * 32 + lg * 8);
        __builtin_amdgcn_s_setprio(1);
#pragma unroll
        for (int mf = 0; mf < 4; ++mf)
#pragma unroll
            for (int nf = 0; nf < 4; ++nf)
                acc[mf][nf] = mfma16(af[mf], bfr[nf], acc[mf][nf]);
        __builtin_amdgcn_s_setprio(0);
        __builtin_amdgcn_s_barrier();   // reads of buf(it&1) done before overwrite
    }

#pragma unroll
    for (int mf = 0; mf < 4; ++mf) {
#pragma unroll
        for (int nf = 0; nf < 4; ++nf) {
#pragma unroll
            for (int r = 0; r < 4; ++r) {
                const int mg = bm * 128 + wr * 64 + mf * 16 + lg * 4 + r;
                const int ng = bn * 128 + wc * 64 + nf * 16 + l15;
                const float v = acc[mf][nf][r] + bias[ng];
                if constexpr (EPI == 2) {
                    const float ge = 0.5f * v * (1.0f + erff(v * 0.70710678118654752f));
                    outb[(size_t)mg * N + ng] = __float2bfloat16(ge);
                } else {
                    const int which = ng >> 10;
                    const int hh = (ng >> 6) & 15;
                    const int dh = ng & 63;
                    const int bb = mg >> 11;
                    const int tt2 = mg & 2047;
                    const int bhid = bb * TH + hh;
                    const __hip_bfloat16 bv = __float2bfloat16(v);
                    if (which == 0)      qb[((size_t)bhid * TT + tt2) * TDH + dh] = bv;
                    else if (which == 1) kb[((size_t)bhid * TT + tt2) * TDH + dh] = bv;
                    else                 vtb[((size_t)bhid * TDH + dh) * TT + tt2] = bv;
                }
            }
        }
    }
}

// ---------------- GEMM split-K-in-block (8 waves): out-proj, FFN2 (N=1024) -------
__global__ __launch_bounds__(512)
void gemm_sk(const __hip_bfloat16* __restrict__ A, const __hip_bfloat16* __restrict__ Bw,
             const float* __restrict__ bias, const float* __restrict__ resid,
             float* __restrict__ outf, int M, int N, int K)
{
    __shared__ char ldsraw[131072];   // [grp][ A buf0|buf1 | B buf0|buf1 ] 4x16KB each
    const int t = threadIdx.x;
    const int tl = t & 255;           // thread index within group
    const int lane = t & 63, w = t >> 6;
    const int grp = w >> 2;           // K-half
    const int wl = w & 3;
    const int wr = wl >> 1, wc = wl & 1;
    const int l15 = lane & 15, lg = lane >> 4;
    const int bn = blockIdx.x, bm = blockIdx.y;

    f32x4 acc[4][4] = {};

    const int Kh = K >> 1;
    const char* Ab = (const char*)(A  + (size_t)bm * 128 * K) + (size_t)grp * Kh * 2;
    const char* Bb = (const char*)(Bw + (size_t)bn * 128 * K) + (size_t)grp * Kh * 2;
    const int pitch = K * 2;
    char* base = ldsraw + grp * 65536;

    const int nt = Kh >> 6;           // out-proj: 8, FFN2: 32
    stage128x128B(Ab, pitch, base, tl);
    stage128x128B(Bb, pitch, base + 32768, tl);

    for (int it = 0; it < nt; ++it) {
        const int cb = (it & 1) * 16384;
        if (it + 1 < nt) {
            const size_t koff = (size_t)(it + 1) * 128;
            const int nb = ((it + 1) & 1) * 16384;
            stage128x128B(Ab + koff, pitch, base + nb, tl);
            stage128x128B(Bb + koff, pitch, base + 32768 + nb, tl);
            asm volatile("s_waitcnt vmcnt(8)" ::: "memory");   // own tile(it) landed
        } else {
            asm volatile("s_waitcnt vmcnt(0)" ::: "memory");
        }
        __builtin_amdgcn_s_barrier();
        __builtin_amdgcn_sched_barrier(0);
        const __hip_bfloat16* bufA = (const __hip_bfloat16*)(base + cb);
        const __hip_bfloat16* bufB = (const __hip_bfloat16*)(base + 32768 + cb);
        bf16x8 af[4][2], bfr[4][2];
#pragma unroll
        for (int mf = 0; mf < 4; ++mf)
#pragma unroll
            for (int kk = 0; kk < 2; ++kk)
                af[mf][kk] = swzfrag(bufA, wr * 64 + mf * 16 + l15, kk * 64 + lg * 16);
#pragma unroll
        for (int nf = 0; nf < 4; ++nf)
#pragma unroll
            for (int kk = 0; kk < 2; ++kk)
                bfr[nf][kk] = swzfrag(bufB, wc * 64 + nf * 16 + l15, kk * 64 + lg * 16);
#pragma unroll
        for (int mf = 0; mf < 4; ++mf)
#pragma unroll
            for (int nf = 0; nf < 4; ++nf) {
                acc[mf][nf] = mfma16(af[mf][0], bfr[nf][0], acc[mf][nf]);
                acc[mf][nf] = mfma16(af[mf][1], bfr[nf][1], acc[mf][nf]);
            }
        __builtin_amdgcn_s_barrier();   // all reads of buf(it&1) done before overwrite
    }

    // ---- cross-group reduce through LDS (loop-end barrier guards reuse) ----
    float* xch = (float*)ldsraw;        // [128][132] fp32 = 67.6 KB
    if (grp == 1) {
#pragma unroll
        for (int mf = 0; mf < 4; ++mf)
#pragma unroll
            for (int nf = 0; nf < 4; ++nf)
#pragma unroll
                for (int r = 0; r < 4; ++r)
                    xch[(wr * 64 + mf * 16 + lg * 4 + r) * 132 + wc * 64 + nf * 16 + l15] =
                        acc[mf][nf][r];
    }
    __syncthreads();
    if (grp == 0) {
#pragma unroll
        for (int mf = 0; mf < 4; ++mf)
#pragma unroll
            for (int nf = 0; nf < 4; ++nf)
#pragma unroll
                for (int r = 0; r < 4; ++r) {
                    const int mgl = wr * 64 + mf * 16 + lg * 4 + r;
                    const int ngl = wc * 64 + nf * 16 + l15;
                    const int mg = bm * 128 + mgl;
                    const int ng = bn * 128 + ngl;
                    const size_t o = (size_t)mg * N + ng;
                    outf[o] = acc[mf][nf][r] + xch[mgl * 132 + ngl] + bias[ng] + resid[o];
                }
    }
}

// ---------------- causal flash attention, 128-row q-blocks (r13) ----------------
__global__ __launch_bounds__(256)
void flash_kernel(const __hip_bfloat16* __restrict__ q, const __hip_bfloat16* __restrict__ k,
                  const __hip_bfloat16* __restrict__ vt, __hip_bfloat16* __restrict__ attn)
{
    const int L  = blockIdx.y * gridDim.x + blockIdx.x;
    const int cu = L & 255;
    const int s  = L >> 8;            // residency slot 0..1
    const int q0 = cu & 15;
    const int qt = s ? (15 - q0) : q0;
    const int bh = s * 16 + (cu >> 4);

    const int t = threadIdx.x;
    const int w = t >> 6, lane = t & 63;
    const int l15 = lane & 15, lg = lane >> 4;
    const int qrow0 = qt * 128 + w * 32;    // wave's first q-row (32 rows: 2 groups)
    const __hip_bfloat16* Qb = q  + (size_t)bh * TT * TDH;
    const __hip_bfloat16* Kb = k  + (size_t)bh * TT * TDH;
    const __hip_bfloat16* Vb = vt + (size_t)bh * TDH * TT;

    __shared__ __hip_bfloat16 kt[2][64 * 64];    // [kv row][d], swizzled (16 KB)
    __shared__ __hip_bfloat16 vtt[2][64 * 64];   // [dh row][kv], swizzled (16 KB)
    __shared__ __hip_bfloat16 plds[4][32 * 64];  // per-wave P tile [q row][kv] (16 KB)

    bf16x8 qa[2][2];
#pragma unroll
    for (int g = 0; g < 2; ++g)
#pragma unroll
        for (int c = 0; c < 2; ++c)
            qa[g][c] = *(const bf16x8*)(Qb + (size_t)(qrow0 + g * 16 + l15) * TDH
                                        + c * 32 + lg * 8);

    f32x4 o[2][4] = {};
    float mrun[2], lrun[2];
#pragma unroll
    for (int g = 0; g < 2; ++g) { mrun[g] = -INFINITY; lrun[g] = 0.0f; }

    const int nt = 2 * qt + 2;        // 64-wide kv tiles (causal, 128 q-rows)
    int cur = 0;
    stage64x128B((const char*)Kb, 128, (char*)kt[0], t);
    stage64x128B((const char*)Vb, TT * 2, (char*)vtt[0], t);
    __syncthreads();

    for (int it = 0; it < nt; ++it) {
        const int kv0 = it * 64;
        if (it + 1 < nt) {
            stage64x128B((const char*)Kb + (size_t)(kv0 + 64) * 128, 128, (char*)kt[cur ^ 1], t);
            stage64x128B((const char*)Vb + (size_t)(kv0 + 64) * 2, TT * 2, (char*)vtt[cur ^ 1], t);
        }
        f32x4 sc[2][4] = {};
        __builtin_amdgcn_s_setprio(1);
#pragma unroll
        for (int j = 0; j < 4; ++j) {
            const bf16x8 kb0 = swzfrag(kt[cur], j * 16 + l15, lg * 16);
            const bf16x8 kb1 = swzfrag(kt[cur], j * 16 + l15, 64 + lg * 16);
            sc[0][j] = mfma16(kb0, qa[0][0], sc[0][j]);
            sc[0][j] = mfma16(kb1, qa[0][1], sc[0][j]);
            sc[1][j] = mfma16(kb0, qa[1][0], sc[1][j]);
            sc[1][j] = mfma16(kb1, qa[1][1], sc[1][j]);
        }
        __builtin_amdgcn_s_setprio(0);
        if (it >= nt - 2) {
#pragma unroll
            for (int g = 0; g < 2; ++g) {
                const int qg = qrow0 + g * 16 + l15;
#pragma unroll
                for (int j = 0; j < 4; ++j)
#pragma unroll
                    for (int r = 0; r < 4; ++r) {
                        const int kvg = kv0 + j * 16 + lg * 4 + r;
                        sc[g][j][r] = (kvg <= qg) ? sc[g][j][r] * 0.125f : -INFINITY;
                    }
            }
        } else {
#pragma unroll
            for (int g = 0; g < 2; ++g)
#pragma unroll
                for (int j = 0; j < 4; ++j)
#pragma unroll
                    for (int r = 0; r < 4; ++r) sc[g][j][r] *= 0.125f;
        }
#pragma unroll
        for (int g = 0; g < 2; ++g) {
            float pm;
            {
                float m0 = fmaxf(fmaxf(sc[g][0][0], sc[g][0][1]), fmaxf(sc[g][0][2], sc[g][0][3]));
                float m1 = fmaxf(fmaxf(sc[g][1][0], sc[g][1][1]), fmaxf(sc[g][1][2], sc[g][1][3]));
                float m2 = fmaxf(fmaxf(sc[g][2][0], sc[g][2][1]), fmaxf(sc[g][2][2], sc[g][2][3]));
                float m3 = fmaxf(fmaxf(sc[g][3][0], sc[g][3][1]), fmaxf(sc[g][3][2], sc[g][3][3]));
                pm = fmaxf(fmaxf(m0, m1), fmaxf(m2, m3));
            }
            pm = fmaxf(pm, __shfl_xor(pm, 16));
            pm = fmaxf(pm, __shfl_xor(pm, 32));

            const float mn = fmaxf(mrun[g], pm);
            const float alpha = __expf(mrun[g] - mn);
            mrun[g] = mn;
            f32x4 p[4];
            float rs = 0.0f;
#pragma unroll
            for (int j = 0; j < 4; ++j) {
                float a = 0.0f;
#pragma unroll
                for (int r = 0; r < 4; ++r) { p[j][r] = __expf(sc[g][j][r] - mn); a += p[j][r]; }
                rs += a;
            }
            rs += __shfl_xor(rs, 16);
            rs += __shfl_xor(rs, 32);
            lrun[g] = lrun[g] * alpha + rs;
#pragma unroll
            for (int nf = 0; nf < 4; ++nf)
#pragma unroll
                for (int r = 0; r < 4; ++r) o[g][nf][r] *= alpha;
            {
                __hip_bfloat16* pw = plds[w];
                const int prow = g * 16 + l15;
#pragma unroll
                for (int j = 0; j < 4; ++j) {
                    ushort4 pk;
                    pk.x = f2bf(p[j][0]); pk.y = f2bf(p[j][1]);
                    pk.z = f2bf(p[j][2]); pk.w = f2bf(p[j][3]);
                    const int cb = j * 32 + lg * 8;
                    *(ushort4*)((char*)pw + prow * 128 + (cb ^ ((prow & 7) << 4))) = pk;
                }
            }
        }
        asm volatile("s_waitcnt lgkmcnt(0)" ::: "memory");
        __builtin_amdgcn_sched_barrier(0);
        bf16x8 pb[2][2];
#pragma unroll
        for (int g = 0; g < 2; ++g)
#pragma unroll
            for (int c = 0; c < 2; ++c)
                pb[g][c] = swzfrag(plds[w], g * 16 + l15, c * 64 + lg * 16);
        __builtin_amdgcn_s_setprio(1);
#pragma unroll
        for (int nf = 0; nf < 4; ++nf) {
            const bf16x8 vb0 = swzfrag(vtt[cur], nf * 16 + l15, lg * 16);
            const bf16x8 vb1 = swzfrag(vtt[cur], nf * 16 + l15, 64 + lg * 16);
            o[0][nf] = mfma16(vb0, pb[0][0], o[0][nf]);
            o[0][nf] = mfma16(vb1, pb[0][1], o[0][nf]);
            o[1][nf] = mfma16(vb0, pb[1][0], o[1][nf]);
            o[1][nf] = mfma16(vb1, pb[1][1], o[1][nf]);
        }
        __builtin_amdgcn_s_setprio(0);
        __syncthreads();
        cur ^= 1;
    }

    const int bb = bh >> 4, hh = bh & 15;
#pragma unroll
    for (int g = 0; g < 2; ++g) {
        const float inv = 1.0f / lrun[g];
        const int tt = qrow0 + g * 16 + l15;
#pragma unroll
        for (int nf = 0; nf < 4; ++nf) {
            const int d0 = nf * 16 + lg * 4;
            ushort4 st;
            st.x = f2bf(o[g][nf][0] * inv);
            st.y = f2bf(o[g][nf][1] * inv);
            st.z = f2bf(o[g][nf][2] * inv);
            st.w = f2bf(o[g][nf][3] * inv);
            *(ushort4*)(attn + ((size_t)(bb * TT + tt)) * TD + hh * TDH + d0) = st;
        }
    }
}

// ---------------- launch ----------------
extern "C" void kernel_launch(void* const* d_in, const int* in_sizes, int n_in,
                              void* d_out, int out_size, void* d_ws, size_t ws_size,
                              hipStream_t stream)
{
    const float* x     = (const float*)d_in[0];
    const float* ln1_g = (const float*)d_in[1];
    const float* ln1_b = (const float*)d_in[2];
    const float* ln2_g = (const float*)d_in[3];
    const float* ln2_b = (const float*)d_in[4];
    const float* w_qkv = (const float*)d_in[5];
    const float* b_qkv = (const float*)d_in[6];
    const float* w_out = (const float*)d_in[7];
    const float* b_out = (const float*)d_in[8];
    const float* w1    = (const float*)d_in[9];
    const float* b1    = (const float*)d_in[10];
    const float* w2    = (const float*)d_in[11];
    const float* b2    = (const float*)d_in[12];

    char* ws = (char*)d_ws;
    __hip_bfloat16* wqkv_bf = (__hip_bfloat16*)(ws + 0);            //  6 MB
    __hip_bfloat16* wout_bf = (__hip_bfloat16*)(ws + 6291456);      //  2 MB
    __hip_bfloat16* w1_bf   = (__hip_bfloat16*)(ws + 8388608);      //  8 MB
    __hip_bfloat16* w2_bf   = (__hip_bfloat16*)(ws + 16777216);     //  8 MB
    float*          x2      = (float*)(ws + 25165824);              // 16 MB
    __hip_bfloat16* hbuf    = (__hip_bfloat16*)(ws + 41943040);     //  8 MB (h, then h2)
    __hip_bfloat16* qbuf    = (__hip_bfloat16*)(ws + 50331648);     //  8 MB
    __hip_bfloat16* kbuf    = (__hip_bfloat16*)(ws + 58720256);     //  8 MB
    __hip_bfloat16* vtbuf   = (__hip_bfloat16*)(ws + 67108864);     //  8 MB
    __hip_bfloat16* attnbuf = (__hip_bfloat16*)(ws + 75497472);     //  8 MB
    __hip_bfloat16* ff1     = (__hip_bfloat16*)(ws + 50331648);     // 32 MB overlay (q/k/vt/attn dead)

    // weights -> bf16 (single fused launch)
    cvt4_kernel<<<12288, 256, 0, stream>>>(w_qkv, w_out, w1, w2,
                                           wqkv_bf, wout_bf, w1_bf, w2_bf);

    // LN1
    ln_kernel<<<TM, 256, 0, stream>>>(x, ln1_g, ln1_b, hbuf);
    // QKV (scatter epilogue), BK=32 linear staging
    gemm_bt32<0><<<dim3(24, 32), 256, 0, stream>>>(hbuf, wqkv_bf, b_qkv,
                                                   nullptr, qbuf, kbuf, vtbuf,
                                                   TM, 3 * TD, TD);
    // attention (128-row q-blocks)
    flash_kernel<<<dim3(16, 32), 256, 0, stream>>>(qbuf, kbuf, vtbuf, attnbuf);
    // out proj + residual -> x2 (fp32), split-K-in-block
    gemm_sk<<<dim3(8, 32), 512, 0, stream>>>(attnbuf, wout_bf, b_out, x,
                                             x2, TM, TD, TD);
    // LN2
    ln_kernel<<<TM, 256, 0, stream>>>(x2, ln2_g, ln2_b, hbuf);
    // FFN1 + GELU -> bf16, BK=32 linear staging
    gemm_bt32<2><<<dim3(32, 32), 256, 0, stream>>>(hbuf, w1_bf, b1,
                                                   ff1, nullptr, nullptr, nullptr,
                                                   TM, TDFF, TD);
    // FFN2 + residual -> d_out (fp32), split-K-in-block
    gemm_sk<<<dim3(8, 32), 512, 0, stream>>>(ff1, w2_bf, b2, x2,
                                             (float*)d_out, TM, TD, TDFF);
}

// Round 19
// 241.994 us; speedup vs baseline: 1.0298x; 1.0298x over previous
//
#include <hip/hip_runtime.h>
#include <hip/hip_bf16.h>
#include <cmath>

// ---------------- types / helpers ----------------
typedef __bf16 bf16x8 __attribute__((ext_vector_type(8)));
typedef float  f32x4  __attribute__((ext_vector_type(4)));

#define LDS_AS __attribute__((address_space(3)))
#define GLB_AS __attribute__((address_space(1)))

__device__ __forceinline__ void gll16(const void* g, void* l) {
    __builtin_amdgcn_global_load_lds((const GLB_AS unsigned int*)g,
                                     (LDS_AS unsigned int*)l, 16, 0, 0);
}

__device__ __forceinline__ f32x4 mfma16(bf16x8 a, bf16x8 b, f32x4 c) {
    return __builtin_amdgcn_mfma_f32_16x16x32_bf16(a, b, c, 0, 0, 0);
}

__device__ __forceinline__ unsigned short f2bf(float f) {
    __hip_bfloat16 b = __float2bfloat16(f);
    return *reinterpret_cast<unsigned short*>(&b);
}

// ---- 128-B-row swizzle (proven 0-conflict; gemm_sk and flash) ----
__device__ __forceinline__ bf16x8 swzfrag(const __hip_bfloat16* __restrict__ lds,
                                          int row, int cb)
{
    const int addr = row * 128 + (cb ^ ((row & 7) << 4));
    return *(const bf16x8*)((const char*)lds + addr);
}

// ---- 64-B-row LINE-swizzle for BK=32 tiles (r12-verified: 0 conflicts) ----
__device__ __forceinline__ bf16x8 swzfrag32(const __hip_bfloat16* __restrict__ lds,
                                            int row, int cb)
{
    const int L = row >> 1;
    const int s = ((row & 1) << 2) | (cb >> 4);
    const int addr = (L << 7) | (((s ^ (L & 7)) << 4) | (cb & 15));
    return *(const bf16x8*)((const char*)lds + addr);
}

// Stage a 128-row x 64-byte (8 KB) BK=32 tile, line-swizzled source, linear LDS.
__device__ __forceinline__ void stage128x64B_swz(const char* __restrict__ base, int pitch,
                                                 char* __restrict__ lds, int t)
{
#pragma unroll
    for (int i = 0; i < 2; ++i) {
        const int d  = i * 4096 + t * 16;
        const int L  = d >> 7;
        const int sp = (d >> 4) & 7;
        const int s  = sp ^ (L & 7);
        const int r  = (L << 1) | (s >> 2);
        const int gx = (s & 3) << 4;
        gll16(base + (size_t)r * pitch + gx, lds + d);
    }
}

// Stage a 64-row x 128-byte tile into LDS, XOR-swizzled (flash). 256 threads.
__device__ __forceinline__ void stage64x128B(const char* __restrict__ base, int pitch,
                                             char* __restrict__ lds, int t)
{
#pragma unroll
    for (int i = 0; i < 2; ++i) {
        const int d   = i * 4096 + t * 16;
        const int row = d >> 7;
        const int x   = d & 127;
        const int gx  = x ^ ((row & 7) << 4);
        gll16(base + (size_t)row * pitch + gx, lds + d);
    }
}

// 128 rows x 128 bytes (16 KB), 256 threads x 4 x 16B. (gemm_sk)
__device__ __forceinline__ void stage128x128B(const char* __restrict__ base, int pitch,
                                              char* __restrict__ lds, int t)
{
#pragma unroll
    for (int i = 0; i < 4; ++i) {
        const int d   = i * 4096 + t * 16;
        const int row = d >> 7;
        const int x   = d & 127;
        const int gx  = x ^ ((row & 7) << 4);
        gll16(base + (size_t)row * pitch + gx, lds + d);
    }
}

// dims
#define TB   2
#define TT   2048
#define TD   1024
#define TH   16
#define TDH  64
#define TDFF 4096
#define TM   4096   // B*T

// ---------------- fused fp32 -> bf16 conversion for ALL 4 weight tensors ---------
__global__ __launch_bounds__(256)
void cvt4_kernel(const float* __restrict__ s0, const float* __restrict__ s1,
                 const float* __restrict__ s2, const float* __restrict__ s3,
                 __hip_bfloat16* __restrict__ d0, __hip_bfloat16* __restrict__ d1,
                 __hip_bfloat16* __restrict__ d2, __hip_bfloat16* __restrict__ d3)
{
    const int i = blockIdx.x * 256 + threadIdx.x;
    const float* src; __hip_bfloat16* dst; int off;
    if (i < 786432)       { src = s0; dst = d0; off = 0; }        // w_qkv  3M f4
    else if (i < 1048576) { src = s1; dst = d1; off = 786432; }   // w_out
    else if (i < 2097152) { src = s2; dst = d2; off = 1048576; }  // w1
    else                  { src = s3; dst = d3; off = 2097152; }  // w2
    const int j = i - off;
    float4 v = ((const float4*)src)[j];
    ushort4 o;
    o.x = f2bf(v.x); o.y = f2bf(v.y); o.z = f2bf(v.z); o.w = f2bf(v.w);
    ((ushort4*)dst)[j] = o;
}

// ---------------- LayerNorm (D=1024), out bf16 ----------------
__global__ __launch_bounds__(256)
void ln_kernel(const float* __restrict__ x, const float* __restrict__ g,
               const float* __restrict__ b, __hip_bfloat16* __restrict__ out)
{
    const int row = blockIdx.x;
    const int t = threadIdx.x;
    const float4 v = *(const float4*)(x + (size_t)row * TD + t * 4);
    float s  = v.x + v.y + v.z + v.w;
    float ss = v.x*v.x + v.y*v.y + v.z*v.z + v.w*v.w;
#pragma unroll
    for (int d = 1; d < 64; d <<= 1) { s += __shfl_xor(s, d); ss += __shfl_xor(ss, d); }
    __shared__ float red[8];
    const int wv = t >> 6, lane = t & 63;
    if (lane == 0) { red[wv] = s; red[4 + wv] = ss; }
    __syncthreads();
    s  = red[0] + red[1] + red[2] + red[3];
    ss = red[4] + red[5] + red[6] + red[7];
    const float mean = s * (1.0f / TD);
    const float var  = ss * (1.0f / TD) - mean * mean;
    const float rstd = rsqrtf(var + 1e-5f);
    const float4 gv = *(const float4*)(g + t * 4);
    const float4 bv = *(const float4*)(b + t * 4);
    ushort4 o;
    o.x = f2bf((v.x - mean) * rstd * gv.x + bv.x);
    o.y = f2bf((v.y - mean) * rstd * gv.y + bv.y);
    o.z = f2bf((v.z - mean) * rstd * gv.z + bv.z);
    o.w = f2bf((v.w - mean) * rstd * gv.w + bv.w);
    *(ushort4*)(out + (size_t)row * TD + t * 4) = o;
}

// ---------------- GEMM BK=32 high-occupancy (QKV, FFN1), 2D XCD chunking -------
// r17-exact core (best measured: 246.7 us total). A and B staged via gll16 +
// line-swizzled LDS (0 conflicts), double-buffered 32 KB -> 4-5 blocks/CU,
// counted vmcnt(4), setprio, 2D XCD-chunked bijective remap.
// r19 delta: vt-scatter in the QKV epilogue packs 4 consecutive-tt values into
// one ushort4 store (was 4x 2-byte scalar stores).
template<int EPI>   // 0 = QKV scatter, 2 = GELU -> bf16
__global__ __launch_bounds__(256)
void gemm_bt32(const __hip_bfloat16* __restrict__ A, const __hip_bfloat16* __restrict__ Bw,
               const float* __restrict__ bias,
               __hip_bfloat16* __restrict__ outb,
               __hip_bfloat16* __restrict__ qb, __hip_bfloat16* __restrict__ kb,
               __hip_bfloat16* __restrict__ vtb,
               int M, int N, int K)
{
    __shared__ __hip_bfloat16 ldsA[2][128 * 32];   // 2 x 8 KB
    __shared__ __hip_bfloat16 ldsB[2][128 * 32];   // 2 x 8 KB  (total 32 KB)
    const int t = threadIdx.x;
    const int lane = t & 63, wv = t >> 6;
    const int wr = wv >> 1, wc = wv & 1;
    const int l15 = lane & 15, lg = lane >> 4;

    // 2D XCD-chunked remap (bijective for gridDim.y==32, gridDim.x multiple of 8)
    const int L   = blockIdx.y * gridDim.x + blockIdx.x;
    const int xcd = L & 7;
    const int sl  = (L >> 3) & 31;
    const int gen = L >> 8;
    const int bm  = xcd * 4 + (sl & 3);
    const int bn  = gen * 8 + (sl >> 2);

    f32x4 acc[4][4] = {};

    const char* Ab = (const char*)(A  + (size_t)bm * 128 * K);
    const char* Bb = (const char*)(Bw + (size_t)bn * 128 * K);
    const int pitch = K * 2;

    const int nt = K >> 5;
    stage128x64B_swz(Ab, pitch, (char*)ldsA[0], t);
    stage128x64B_swz(Bb, pitch, (char*)ldsB[0], t);

    for (int it = 0; it < nt; ++it) {
        if (it + 1 < nt) {
            const size_t koff = (size_t)(it + 1) * 64;   // 32 elems = 64 B per row
            stage128x64B_swz(Ab + koff, pitch, (char*)ldsA[(it + 1) & 1], t);
            stage128x64B_swz(Bb + koff, pitch, (char*)ldsB[(it + 1) & 1], t);
            asm volatile("s_waitcnt vmcnt(4)" ::: "memory");   // tile(it) landed
        } else {
            asm volatile("s_waitcnt vmcnt(0)" ::: "memory");
        }
        __builtin_amdgcn_s_barrier();
        __builtin_amdgcn_sched_barrier(0);
        const __hip_bfloat16* bufA = ldsA[it & 1];
        const __hip_bfloat16* bufB = ldsB[it & 1];
        bf16x8 af[4], bfr[4];
#pragma unroll
        for (int mf = 0; mf < 4; ++mf)
            af[mf] = swzfrag32(bufA, wr * 64 + mf * 16 + l15, lg * 16);
#pragma unroll
        for (int nf = 0; nf < 4; ++nf)
            bfr[nf] = swzfrag32(bufB, wc * 64 + nf * 16 + l15, lg * 16);
        __builtin_amdgcn_s_setprio(1);
#pragma unroll
        for (int mf = 0; mf < 4; ++mf)
#pragma unroll
            for (int nf = 0; nf < 4; ++nf)
                acc[mf][nf] = mfma16(af[mf], bfr[nf], acc[mf][nf]);
        __builtin_amdgcn_s_setprio(0);
        __builtin_amdgcn_s_barrier();   // reads of buf(it&1) done before overwrite
    }

#pragma unroll
    for (int mf = 0; mf < 4; ++mf) {
#pragma unroll
        for (int nf = 0; nf < 4; ++nf) {
            const int mg0 = bm * 128 + wr * 64 + mf * 16 + lg * 4;
            const int ng  = bn * 128 + wc * 64 + nf * 16 + l15;
            if constexpr (EPI == 2) {
#pragma unroll
                for (int r = 0; r < 4; ++r) {
                    const float v = acc[mf][nf][r] + bias[ng];
                    const float ge = 0.5f * v * (1.0f + erff(v * 0.70710678118654752f));
                    outb[(size_t)(mg0 + r) * N + ng] = __float2bfloat16(ge);
                }
            } else {
                const int which = ng >> 10;
                const int hh = (ng >> 6) & 15;
                const int dh = ng & 63;
                const int bb = mg0 >> 11;
                const int tt0 = mg0 & 2047;           // mg0 % 4 == 0: no row crossing
                const int bhid = bb * TH + hh;
                const float bs = bias[ng];
                if (which == 2) {
                    // packed vt scatter: 4 consecutive tt in one 8-B store
                    ushort4 pk;
                    pk.x = f2bf(acc[mf][nf][0] + bs);
                    pk.y = f2bf(acc[mf][nf][1] + bs);
                    pk.z = f2bf(acc[mf][nf][2] + bs);
                    pk.w = f2bf(acc[mf][nf][3] + bs);
                    *(ushort4*)(vtb + ((size_t)bhid * TDH + dh) * TT + tt0) = pk;
                } else {
                    __hip_bfloat16* dst = (which == 0) ? qb : kb;
#pragma unroll
                    for (int r = 0; r < 4; ++r)
                        dst[((size_t)bhid * TT + tt0 + r) * TDH + dh] =
                            __float2bfloat16(acc[mf][nf][r] + bs);
                }
            }
        }
    }
}

// ---------------- GEMM split-K-in-block (8 waves): out-proj, FFN2 (N=1024) -------
__global__ __launch_bounds__(512)
void gemm_sk(const __hip_bfloat16* __restrict__ A, const __hip_bfloat16* __restrict__ Bw,
             const float* __restrict__ bias, const float* __restrict__ resid,
             float* __restrict__ outf, int M, int N, int K)
{
    __shared__ char ldsraw[131072];   // [grp][ A buf0|buf1 | B buf0|buf1 ] 4x16KB each
    const int t = threadIdx.x;
    const int tl = t & 255;           // thread index within group
    const int lane = t & 63, w = t >> 6;
    const int grp = w >> 2;           // K-half
    const int wl = w & 3;
    const int wr = wl >> 1, wc = wl & 1;
    const int l15 = lane & 15, lg = lane >> 4;
    const int bn = blockIdx.x, bm = blockIdx.y;

    f32x4 acc[4][4] = {};

    const int Kh = K >> 1;
    const char* Ab = (const char*)(A  + (size_t)bm * 128 * K) + (size_t)grp * Kh * 2;
    const char* Bb = (const char*)(Bw + (size_t)bn * 128 * K) + (size_t)grp * Kh * 2;
    const int pitch = K * 2;
    char* base = ldsraw + grp * 65536;

    const int nt = Kh >> 6;           // out-proj: 8, FFN2: 32
    stage128x128B(Ab, pitch, base, tl);
    stage128x128B(Bb, pitch, base + 32768, tl);

    for (int it = 0; it < nt; ++it) {
        const int cb = (it & 1) * 16384;
        if (it + 1 < nt) {
            const size_t koff = (size_t)(it + 1) * 128;
            const int nb = ((it + 1) & 1) * 16384;
            stage128x128B(Ab + koff, pitch, base + nb, tl);
            stage128x128B(Bb + koff, pitch, base + 32768 + nb, tl);
            asm volatile("s_waitcnt vmcnt(8)" ::: "memory");   // own tile(it) landed
        } else {
            asm volatile("s_waitcnt vmcnt(0)" ::: "memory");
        }
        __builtin_amdgcn_s_barrier();
        __builtin_amdgcn_sched_barrier(0);
        const __hip_bfloat16* bufA = (const __hip_bfloat16*)(base + cb);
        const __hip_bfloat16* bufB = (const __hip_bfloat16*)(base + 32768 + cb);
        bf16x8 af[4][2], bfr[4][2];
#pragma unroll
        for (int mf = 0; mf < 4; ++mf)
#pragma unroll
            for (int kk = 0; kk < 2; ++kk)
                af[mf][kk] = swzfrag(bufA, wr * 64 + mf * 16 + l15, kk * 64 + lg * 16);
#pragma unroll
        for (int nf = 0; nf < 4; ++nf)
#pragma unroll
            for (int kk = 0; kk < 2; ++kk)
                bfr[nf][kk] = swzfrag(bufB, wc * 64 + nf * 16 + l15, kk * 64 + lg * 16);
#pragma unroll
        for (int mf = 0; mf < 4; ++mf)
#pragma unroll
            for (int nf = 0; nf < 4; ++nf) {
                acc[mf][nf] = mfma16(af[mf][0], bfr[nf][0], acc[mf][nf]);
                acc[mf][nf] = mfma16(af[mf][1], bfr[nf][1], acc[mf][nf]);
            }
        __builtin_amdgcn_s_barrier();   // all reads of buf(it&1) done before overwrite
    }

    // ---- cross-group reduce through LDS (loop-end barrier guards reuse) ----
    float* xch = (float*)ldsraw;        // [128][132] fp32 = 67.6 KB
    if (grp == 1) {
#pragma unroll
        for (int mf = 0; mf < 4; ++mf)
#pragma unroll
            for (int nf = 0; nf < 4; ++nf)
#pragma unroll
                for (int r = 0; r < 4; ++r)
                    xch[(wr * 64 + mf * 16 + lg * 4 + r) * 132 + wc * 64 + nf * 16 + l15] =
                        acc[mf][nf][r];
    }
    __syncthreads();
    if (grp == 0) {
#pragma unroll
        for (int mf = 0; mf < 4; ++mf)
#pragma unroll
            for (int nf = 0; nf < 4; ++nf)
#pragma unroll
                for (int r = 0; r < 4; ++r) {
                    const int mgl = wr * 64 + mf * 16 + lg * 4 + r;
                    const int ngl = wc * 64 + nf * 16 + l15;
                    const int mg = bm * 128 + mgl;
                    const int ng = bn * 128 + ngl;
                    const size_t o = (size_t)mg * N + ng;
                    outf[o] = acc[mf][nf][r] + xch[mgl * 132 + ngl] + bias[ng] + resid[o];
                }
    }
}

// ---------------- causal flash attention, 128-row q-blocks (r13) ----------------
__global__ __launch_bounds__(256)
void flash_kernel(const __hip_bfloat16* __restrict__ q, const __hip_bfloat16* __restrict__ k,
                  const __hip_bfloat16* __restrict__ vt, __hip_bfloat16* __restrict__ attn)
{
    const int L  = blockIdx.y * gridDim.x + blockIdx.x;
    const int cu = L & 255;
    const int s  = L >> 8;            // residency slot 0..1
    const int q0 = cu & 15;
    const int qt = s ? (15 - q0) : q0;
    const int bh = s * 16 + (cu >> 4);

    const int t = threadIdx.x;
    const int w = t >> 6, lane = t & 63;
    const int l15 = lane & 15, lg = lane >> 4;
    const int qrow0 = qt * 128 + w * 32;    // wave's first q-row (32 rows: 2 groups)
    const __hip_bfloat16* Qb = q  + (size_t)bh * TT * TDH;
    const __hip_bfloat16* Kb = k  + (size_t)bh * TT * TDH;
    const __hip_bfloat16* Vb = vt + (size_t)bh * TDH * TT;

    __shared__ __hip_bfloat16 kt[2][64 * 64];    // [kv row][d], swizzled (16 KB)
    __shared__ __hip_bfloat16 vtt[2][64 * 64];   // [dh row][kv], swizzled (16 KB)
    __shared__ __hip_bfloat16 plds[4][32 * 64];  // per-wave P tile [q row][kv] (16 KB)

    bf16x8 qa[2][2];
#pragma unroll
    for (int g = 0; g < 2; ++g)
#pragma unroll
        for (int c = 0; c < 2; ++c)
            qa[g][c] = *(const bf16x8*)(Qb + (size_t)(qrow0 + g * 16 + l15) * TDH
                                        + c * 32 + lg * 8);

    f32x4 o[2][4] = {};
    float mrun[2], lrun[2];
#pragma unroll
    for (int g = 0; g < 2; ++g) { mrun[g] = -INFINITY; lrun[g] = 0.0f; }

    const int nt = 2 * qt + 2;        // 64-wide kv tiles (causal, 128 q-rows)
    int cur = 0;
    stage64x128B((const char*)Kb, 128, (char*)kt[0], t);
    stage64x128B((const char*)Vb, TT * 2, (char*)vtt[0], t);
    __syncthreads();

    for (int it = 0; it < nt; ++it) {
        const int kv0 = it * 64;
        if (it + 1 < nt) {
            stage64x128B((const char*)Kb + (size_t)(kv0 + 64) * 128, 128, (char*)kt[cur ^ 1], t);
            stage64x128B((const char*)Vb + (size_t)(kv0 + 64) * 2, TT * 2, (char*)vtt[cur ^ 1], t);
        }
        f32x4 sc[2][4] = {};
        __builtin_amdgcn_s_setprio(1);
#pragma unroll
        for (int j = 0; j < 4; ++j) {
            const bf16x8 kb0 = swzfrag(kt[cur], j * 16 + l15, lg * 16);
            const bf16x8 kb1 = swzfrag(kt[cur], j * 16 + l15, 64 + lg * 16);
            sc[0][j] = mfma16(kb0, qa[0][0], sc[0][j]);
            sc[0][j] = mfma16(kb1, qa[0][1], sc[0][j]);
            sc[1][j] = mfma16(kb0, qa[1][0], sc[1][j]);
            sc[1][j] = mfma16(kb1, qa[1][1], sc[1][j]);
        }
        __builtin_amdgcn_s_setprio(0);
        if (it >= nt - 2) {
#pragma unroll
            for (int g = 0; g < 2; ++g) {
                const int qg = qrow0 + g * 16 + l15;
#pragma unroll
                for (int j = 0; j < 4; ++j)
#pragma unroll
                    for (int r = 0; r < 4; ++r) {
                        const int kvg = kv0 + j * 16 + lg * 4 + r;
                        sc[g][j][r] = (kvg <= qg) ? sc[g][j][r] * 0.125f : -INFINITY;
                    }
            }
        } else {
#pragma unroll
            for (int g = 0; g < 2; ++g)
#pragma unroll
                for (int j = 0; j < 4; ++j)
#pragma unroll
                    for (int r = 0; r < 4; ++r) sc[g][j][r] *= 0.125f;
        }
#pragma unroll
        for (int g = 0; g < 2; ++g) {
            float pm;
            {
                float m0 = fmaxf(fmaxf(sc[g][0][0], sc[g][0][1]), fmaxf(sc[g][0][2], sc[g][0][3]));
                float m1 = fmaxf(fmaxf(sc[g][1][0], sc[g][1][1]), fmaxf(sc[g][1][2], sc[g][1][3]));
                float m2 = fmaxf(fmaxf(sc[g][2][0], sc[g][2][1]), fmaxf(sc[g][2][2], sc[g][2][3]));
                float m3 = fmaxf(fmaxf(sc[g][3][0], sc[g][3][1]), fmaxf(sc[g][3][2], sc[g][3][3]));
                pm = fmaxf(fmaxf(m0, m1), fmaxf(m2, m3));
            }
            pm = fmaxf(pm, __shfl_xor(pm, 16));
            pm = fmaxf(pm, __shfl_xor(pm, 32));

            const float mn = fmaxf(mrun[g], pm);
            const float alpha = __expf(mrun[g] - mn);
            mrun[g] = mn;
            f32x4 p[4];
            float rs = 0.0f;
#pragma unroll
            for (int j = 0; j < 4; ++j) {
                float a = 0.0f;
#pragma unroll
                for (int r = 0; r < 4; ++r) { p[j][r] = __expf(sc[g][j][r] - mn); a += p[j][r]; }
                rs += a;
            }
            rs += __shfl_xor(rs, 16);
            rs += __shfl_xor(rs, 32);
            lrun[g] = lrun[g] * alpha + rs;
#pragma unroll
            for (int nf = 0; nf < 4; ++nf)
#pragma unroll
                for (int r = 0; r < 4; ++r) o[g][nf][r] *= alpha;
            {
                __hip_bfloat16* pw = plds[w];
                const int prow = g * 16 + l15;
#pragma unroll
                for (int j = 0; j < 4; ++j) {
                    ushort4 pk;
                    pk.x = f2bf(p[j][0]); pk.y = f2bf(p[j][1]);
                    pk.z = f2bf(p[j][2]); pk.w = f2bf(p[j][3]);
                    const int cb = j * 32 + lg * 8;
                    *(ushort4*)((char*)pw + prow * 128 + (cb ^ ((prow & 7) << 4))) = pk;
                }
            }
        }
        asm volatile("s_waitcnt lgkmcnt(0)" ::: "memory");
        __builtin_amdgcn_sched_barrier(0);
        bf16x8 pb[2][2];
#pragma unroll
        for (int g = 0; g < 2; ++g)
#pragma unroll
            for (int c = 0; c < 2; ++c)
                pb[g][c] = swzfrag(plds[w], g * 16 + l15, c * 64 + lg * 16);
        __builtin_amdgcn_s_setprio(1);
#pragma unroll
        for (int nf = 0; nf < 4; ++nf) {
            const bf16x8 vb0 = swzfrag(vtt[cur], nf * 16 + l15, lg * 16);
            const bf16x8 vb1 = swzfrag(vtt[cur], nf * 16 + l15, 64 + lg * 16);
            o[0][nf] = mfma16(vb0, pb[0][0], o[0][nf]);
            o[0][nf] = mfma16(vb1, pb[0][1], o[0][nf]);
            o[1][nf] = mfma16(vb0, pb[1][0], o[1][nf]);
            o[1][nf] = mfma16(vb1, pb[1][1], o[1][nf]);
        }
        __builtin_amdgcn_s_setprio(0);
        __syncthreads();
        cur ^= 1;
    }

    const int bb = bh >> 4, hh = bh & 15;
#pragma unroll
    for (int g = 0; g < 2; ++g) {
        const float inv = 1.0f / lrun[g];
        const int tt = qrow0 + g * 16 + l15;
#pragma unroll
        for (int nf = 0; nf < 4; ++nf) {
            const int d0 = nf * 16 + lg * 4;
            ushort4 st;
            st.x = f2bf(o[g][nf][0] * inv);
            st.y = f2bf(o[g][nf][1] * inv);
            st.z = f2bf(o[g][nf][2] * inv);
            st.w = f2bf(o[g][nf][3] * inv);
            *(ushort4*)(attn + ((size_t)(bb * TT + tt)) * TD + hh * TDH + d0) = st;
        }
    }
}

// ---------------- launch ----------------
extern "C" void kernel_launch(void* const* d_in, const int* in_sizes, int n_in,
                              void* d_out, int out_size, void* d_ws, size_t ws_size,
                              hipStream_t stream)
{
    const float* x     = (const float*)d_in[0];
    const float* ln1_g = (const float*)d_in[1];
    const float* ln1_b = (const float*)d_in[2];
    const float* ln2_g = (const float*)d_in[3];
    const float* ln2_b = (const float*)d_in[4];
    const float* w_qkv = (const float*)d_in[5];
    const float* b_qkv = (const float*)d_in[6];
    const float* w_out = (const float*)d_in[7];
    const float* b_out = (const float*)d_in[8];
    const float* w1    = (const float*)d_in[9];
    const float* b1    = (const float*)d_in[10];
    const float* w2    = (const float*)d_in[11];
    const float* b2    = (const float*)d_in[12];

    char* ws = (char*)d_ws;
    __hip_bfloat16* wqkv_bf = (__hip_bfloat16*)(ws + 0);            //  6 MB
    __hip_bfloat16* wout_bf = (__hip_bfloat16*)(ws + 6291456);      //  2 MB
    __hip_bfloat16* w1_bf   = (__hip_bfloat16*)(ws + 8388608);      //  8 MB
    __hip_bfloat16* w2_bf   = (__hip_bfloat16*)(ws + 16777216);     //  8 MB
    float*          x2      = (float*)(ws + 25165824);              // 16 MB
    __hip_bfloat16* hbuf    = (__hip_bfloat16*)(ws + 41943040);     //  8 MB (h, then h2)
    __hip_bfloat16* qbuf    = (__hip_bfloat16*)(ws + 50331648);     //  8 MB
    __hip_bfloat16* kbuf    = (__hip_bfloat16*)(ws + 58720256);     //  8 MB
    __hip_bfloat16* vtbuf   = (__hip_bfloat16*)(ws + 67108864);     //  8 MB
    __hip_bfloat16* attnbuf = (__hip_bfloat16*)(ws + 75497472);     //  8 MB
    __hip_bfloat16* ff1     = (__hip_bfloat16*)(ws + 50331648);     // 32 MB overlay (q/k/vt/attn dead)

    // weights -> bf16 (single fused launch)
    cvt4_kernel<<<12288, 256, 0, stream>>>(w_qkv, w_out, w1, w2,
                                           wqkv_bf, wout_bf, w1_bf, w2_bf);

    // LN1
    ln_kernel<<<TM, 256, 0, stream>>>(x, ln1_g, ln1_b, hbuf);
    // QKV (scatter epilogue), BK=32 + 2D XCD chunking
    gemm_bt32<0><<<dim3(24, 32), 256, 0, stream>>>(hbuf, wqkv_bf, b_qkv,
                                                   nullptr, qbuf, kbuf, vtbuf,
                                                   TM, 3 * TD, TD);
    // attention (128-row q-blocks)
    flash_kernel<<<dim3(16, 32), 256, 0, stream>>>(qbuf, kbuf, vtbuf, attnbuf);
    // out proj + residual -> x2 (fp32), split-K-in-block
    gemm_sk<<<dim3(8, 32), 512, 0, stream>>>(attnbuf, wout_bf, b_out, x,
                                             x2, TM, TD, TD);
    // LN2
    ln_kernel<<<TM, 256, 0, stream>>>(x2, ln2_g, ln2_b, hbuf);
    // FFN1 + GELU -> bf16, BK=32 + 2D XCD chunking
    gemm_bt32<2><<<dim3(32, 32), 256, 0, stream>>>(hbuf, w1_bf, b1,
                                                   ff1, nullptr, nullptr, nullptr,
                                                   TM, TDFF, TD);
    // FFN2 + residual -> d_out (fp32), split-K-in-block
    gemm_sk<<<dim3(8, 32), 512, 0, stream>>>(ff1, w2_bf, b2, x2,
                                             (float*)d_out, TM, TD, TDFF);
}